// Round 1
// baseline (219.011 us; speedup 1.0000x reference)
//
#include <hip/hip_runtime.h>
#include <hip/hip_bf16.h>

typedef unsigned short u16;
typedef __attribute__((ext_vector_type(4))) float f32x4;
typedef __attribute__((ext_vector_type(8))) short bf16x8;

#define HDIM 128

__device__ __forceinline__ short f2b(float x) {
  union { __hip_bfloat16 b; short s; } u;
  u.b = __float2bfloat16(x);
  return u.s;
}

// Gather weight[samples] -> bf16 rows, fold 2*(bias - noise_logits) per sample,
// zero the global accumulator (d_ws is poisoned 0xAA before every launch).
__global__ void prep_kernel(const float* __restrict__ weight,
                            const float* __restrict__ bias,
                            const float* __restrict__ nlog,
                            const int* __restrict__ samples,
                            u16* __restrict__ wsb,
                            float* __restrict__ ck2,
                            float* __restrict__ acc) {
  const int k = blockIdx.x;
  const int s = samples[k];
  wsb[k * HDIM + threadIdx.x] = (u16)f2b(weight[(size_t)s * HDIM + threadIdx.x]);
  if (threadIdx.x == 0) {
    ck2[k] = 2.0f * (bias[s] - nlog[s]);
    if (k == 0) acc[0] = 0.0f;
  }
}

// One wave = 16 rows. 4 waves/block = 64 rows/block. Grid = N/64.
__launch_bounds__(256, 2)
__global__ void loss_kernel(const float* __restrict__ hiddens,
                            const float* __restrict__ weight,
                            const float* __restrict__ bias,
                            const float* __restrict__ nlog,
                            const int* __restrict__ targets,
                            const u16* __restrict__ wsb,
                            const float* __restrict__ ck2,
                            float* __restrict__ acc) {
  __shared__ float sc[64 * 256];   // 64 KB: y = 2*score + 2*(bias-nl), swizzled
  const int tid  = threadIdx.x;
  const int lane = tid & 63;
  const int wave = tid >> 6;
  const int m    = lane & 15;      // MFMA m-index / row-in-wave-tile
  const int quad = lane >> 4;      // k-group for A/B frags, row-quad for C
  const int wrow = wave * 16;
  const int row  = blockIdx.x * 64 + wrow + m;

  const float* __restrict__ hrow = hiddens + (size_t)row * HDIM;

  // ---- Phase 1: target score, fp32 (each quad covers 32 of 128 h-elems) ----
  const int tgt = targets[row];
  const float* __restrict__ trow = weight + (size_t)tgt * HDIM;
  float p = 0.0f;
#pragma unroll
  for (int j = 0; j < 8; ++j) {
    const float4 hv = *reinterpret_cast<const float4*>(hrow + quad * 32 + j * 4);
    const float4 wv = *reinterpret_cast<const float4*>(trow + quad * 32 + j * 4);
    p += hv.x * wv.x + hv.y * wv.y + hv.z * wv.z + hv.w * wv.w;
  }
  p += __shfl_xor(p, 16);
  p += __shfl_xor(p, 32);
  const float y0 = 2.0f * (p + bias[tgt] - nlog[tgt]);  // 2*out0

  // ---- Phase 2: A fragments (fp32 -> bf16 in-register). A[m][k], k=quad*8+j ----
  bf16x8 af[4];
#pragma unroll
  for (int kq = 0; kq < 4; ++kq) {
    const float4 f0 = *reinterpret_cast<const float4*>(hrow + kq * 32 + quad * 8);
    const float4 f1 = *reinterpret_cast<const float4*>(hrow + kq * 32 + quad * 8 + 4);
    bf16x8 a;
    a[0] = f2b(f0.x); a[1] = f2b(f0.y); a[2] = f2b(f0.z); a[3] = f2b(f0.w);
    a[4] = f2b(f1.x); a[5] = f2b(f1.y); a[6] = f2b(f1.z); a[7] = f2b(f1.w);
    af[kq] = a;
  }

  // ---- Phase 3: 16 col-tiles of 16: 4 MFMAs each, write y=2*score+ck2 to LDS ----
#pragma unroll 4
  for (int ct = 0; ct < 16; ++ct) {
    const int col = ct * 16 + m;                  // MFMA n-index
    const u16* __restrict__ bp = wsb + (size_t)col * HDIM;
    f32x4 c = {0.f, 0.f, 0.f, 0.f};
#pragma unroll
    for (int kq = 0; kq < 4; ++kq) {
      const bf16x8 bf = *reinterpret_cast<const bf16x8*>(bp + kq * 32 + quad * 8);
      c = __builtin_amdgcn_mfma_f32_16x16x32_bf16(af[kq], bf, c, 0, 0, 0);
    }
    const float ckv = ck2[col];
#pragma unroll
    for (int r = 0; r < 4; ++r) {
      const int rl = quad * 4 + r;                // C/D: row = quad*4 + reg
      const int cs = col ^ ((rl & 7) << 2);       // XOR swizzle -> 2-way writes
      sc[(wrow + rl) * 256 + cs] = 2.0f * c[r] + ckv;
    }
  }
  __syncthreads();

  // ---- Phase 4: res0 = -0.5*log(1 + sum_k exp(y_k - y0)) (no max needed) ----
  // lane covers row (wrow+m), quarter `quad` of the 256 cols; rotated read
  // order so banks = (j + m + quad*16) & 31 -> 2-way (free).
  const int roff = (wrow + m) * 256 + quad * 64;
  const int rot  = (m + quad * 16) & 63;
  float s = 0.0f;
#pragma unroll 16
  for (int j = 0; j < 64; ++j) {
    const float v = sc[roff + ((j + rot) & 63)];
    s += __expf(v - y0);
  }
  s += __shfl_xor(s, 16);
  s += __shfl_xor(s, 32);
  float res0 = -0.5f * __logf(s + 1.0f);          // +1 = target's own exp(0)
  res0 += __shfl_xor(res0, 1);
  res0 += __shfl_xor(res0, 2);
  res0 += __shfl_xor(res0, 4);
  res0 += __shfl_xor(res0, 8);
  if (lane == 0) atomicAdd(acc, res0);            // one atomic per wave
}

__global__ void finish_kernel(const float* __restrict__ acc,
                              float* __restrict__ out, float scale) {
  out[0] = acc[0] * scale;  // scale = -1/N
}

extern "C" void kernel_launch(void* const* d_in, const int* in_sizes, int n_in,
                              void* d_out, int out_size, void* d_ws, size_t ws_size,
                              hipStream_t stream) {
  const float* weight  = (const float*)d_in[0];
  const float* bias    = (const float*)d_in[1];
  const float* hiddens = (const float*)d_in[2];
  const float* nlog    = (const float*)d_in[3];
  const int*   targets = (const int*)d_in[4];
  const int*   samples = (const int*)d_in[5];
  const int N = in_sizes[2] / HDIM;   // 32768
  const int K = in_sizes[5];          // 256

  u16*   wsb = (u16*)d_ws;
  float* ck2 = (float*)((char*)d_ws + (size_t)K * HDIM * sizeof(u16));
  float* acc = ck2 + K;

  prep_kernel<<<K, HDIM, 0, stream>>>(weight, bias, nlog, samples, wsb, ck2, acc);
  loss_kernel<<<N / 64, 256, 0, stream>>>(hiddens, weight, bias, nlog, targets,
                                          wsb, ck2, acc);
  finish_kernel<<<1, 1, 0, stream>>>(acc, (float*)d_out, -1.0f / (float)N);
}